// Round 9
// baseline (644.743 us; speedup 1.0000x reference)
//
#include <hip/hip_runtime.h>

// EMA Vector-Quantizer for MI355X (gfx950).
// N=16384 tokens, D=64, K=8192. Dominant cost: 16384x8192x64 fp32 GEMM for
// distance argmin (no fp32 MFMA on CDNA4 -> VALU, 109 us FMA-issue floor).
// R8 falsified per-pipe models: R2 (w-in-LDS+conflicts), R4 (AGPR shuttles),
// R8 (clean, VGPR=104) all land ~330-340 us -> latency-exposure invariant at
// 2 waves/SIMD (w loads L1-miss -> ~200-300cyc L2 latency; only ~128 FMA-issue
// cyc of cover between dependent waits; true VALUBusy ~30%).
// R9: TN=256 (16n x 8k per thread, acc=128 regs) doubles FMA per w-load and
// halves w lane-traffic; manual 1-deep software pipeline over d gives every
// load a full 128-FMA burst of latency cover. z_s = 64KB -> 2 blocks/CU
// naturally -> 256-VGPR budget (no dummy pad needed). Grid (64,8)=512 blocks
// = exactly 2/CU, single pass.

#define N_TOK 16384
#define K_EMB 8192
#define EMB_D 64
#define TN 256
#define GROUPS 8
#define KPG (K_EMB / GROUPS)   // 1024 codes per k-group, 8 kb-tiles of 128

// d_out flat layout (float32), in reference return order:
// z_q (1048576) | loss | new_weight (524288) | new_cluster_size (8192) | new_embed_avg (524288)
#define OFF_LOSS 1048576
#define OFF_W    1048577
#define OFF_CS   1572865
#define OFF_EA   1581057

// scratch inside the z_q region of out (all < 1048576, overwritten by k_quant)
#define OUT_WT 0                        // w_t[d][k]: 64 x 8192 = 524288 floats
#define OUT_CD 524288                   // cand dist [GROUPS][N_TOK] = 131072
#define OUT_CI (524288 + 131072)        // cand idx  [GROUPS][N_TOK] = 131072

// ws float offsets
#define WS_NSUM  0
#define WS_LOSS  1
#define WS_WNORM 16
#define WS_IDX   (WS_WNORM + K_EMB)

// ---------------------------------------------------------------------------
// K0: wnorm[k]; transpose weight -> w_t[d][k] (in out); zero accumulators.
__global__ void k_prep(const float* __restrict__ weight,
                       float* __restrict__ out, float* __restrict__ ws) {
  int gid = blockIdx.x * 256 + threadIdx.x;     // 0..131071
  int row = gid >> 4;                            // codebook row 0..8191
  int l16 = gid & 15;
  float4 w4 = *(const float4*)(weight + row * EMB_D + l16 * 4);
  float s = w4.x * w4.x + w4.y * w4.y + w4.z * w4.z + w4.w * w4.w;
  #pragma unroll
  for (int off = 8; off > 0; off >>= 1) s += __shfl_xor(s, off, 16);
  if (l16 == 0) ws[WS_WNORM + row] = s;

  // transposed copy: w_t[d*8192 + row], d = l16*4+c
  out[OUT_WT + (l16 * 4 + 0) * K_EMB + row] = w4.x;
  out[OUT_WT + (l16 * 4 + 1) * K_EMB + row] = w4.y;
  out[OUT_WT + (l16 * 4 + 2) * K_EMB + row] = w4.z;
  out[OUT_WT + (l16 * 4 + 3) * K_EMB + row] = w4.w;

  #pragma unroll
  for (int j = 0; j < 4; ++j) out[OFF_EA + gid * 4 + j] = 0.f;
  if (gid < K_EMB) out[OFF_CS + gid] = 0.f;
  if (gid == 0) { out[OFF_LOSS] = 0.f; ws[WS_NSUM] = 0.f; ws[WS_LOSS] = 0.f; }
}

// ---------------------------------------------------------------------------
// K1: distance argmin. Block tile 256n x 1024k; thread tile 16n x 8k.
// grid (64, 8) x 256 threads = 512 blocks = exactly 2/CU (64KB LDS cap ->
// 256-VGPR budget; acc[16][8]=128 regs stays in arch VGPRs).
// w fragment: k = ktb + g*64 + tx*4 + j -> contiguous dwordx4 from w_t rows.
// z fragment: LDS broadcast. d-loop is 1-deep software-pipelined.
__global__ __launch_bounds__(256, 2) void k_argmin(
    const float* __restrict__ z, const float* __restrict__ wt,
    const float* __restrict__ wnorm, float* __restrict__ cd,
    int* __restrict__ ci) {
  __shared__ __align__(16) float z_s[EMB_D * TN];  // [d][n], 64 KB
  const int t = threadIdx.x;
  const int n0 = blockIdx.x * TN;
  const int kbase = blockIdx.y * KPG;
  // z is (b, c, hw): z_flat[n][d] = z[b*65536 + d*1024 + hw], n = b*1024+hw.
  // TN=256 stays within one b-slab (n0 multiple of 256, 1024-aligned slabs).
  const float* zb = z + ((n0 >> 10) << 16) + (n0 & 1023);

  #pragma unroll
  for (int i = 0; i < 16; ++i) {
    int f4 = i * 256 + t;                 // 0..4095 float4s
    int d = f4 >> 6, c4 = (f4 & 63) * 4;
    *(float4*)(z_s + d * TN + c4) = *(const float4*)(zb + d * 1024 + c4);
  }
  __syncthreads();                        // the only barrier

  const int tx = t & 15, ty = t >> 4;     // tx -> k, ty -> 16-row n slab
  const float* zrow = z_s + ty * 16;      // this thread's n-slab base
  float bestd[16];
  int besti[16];
  #pragma unroll
  for (int i = 0; i < 16; ++i) { bestd[i] = 3.4e38f; besti[i] = 0; }

  for (int kb = 0; kb < KPG / 128; ++kb) {
    const int ktb = kbase + kb * 128;
    float4 wn0 = *(const float4*)(wnorm + ktb + tx * 4);
    float4 wn1 = *(const float4*)(wnorm + ktb + 64 + tx * 4);

    float acc[16][8];
    #pragma unroll
    for (int i = 0; i < 16; ++i)
      #pragma unroll
      for (int j = 0; j < 8; ++j) acc[i][j] = 0.f;

    const float* wp = wt + ktb + tx * 4;  // row stride K_EMB per d

    // software pipeline: prefetch d+1 while computing d
    float4 pz0 = *(const float4*)(zrow);
    float4 pz1 = *(const float4*)(zrow + 4);
    float4 pz2 = *(const float4*)(zrow + 8);
    float4 pz3 = *(const float4*)(zrow + 12);
    float4 pw0 = *(const float4*)(wp);
    float4 pw1 = *(const float4*)(wp + 64);

    #pragma unroll 4
    for (int d = 0; d < EMB_D; ++d) {
      float4 z0 = pz0, z1 = pz1, z2 = pz2, z3 = pz3;
      float4 w0 = pw0, w1 = pw1;
      if (d + 1 < EMB_D) {
        const float* zn = zrow + (d + 1) * TN;
        const float* wn = wp + (d + 1) * K_EMB;
        pz0 = *(const float4*)(zn);
        pz1 = *(const float4*)(zn + 4);
        pz2 = *(const float4*)(zn + 8);
        pz3 = *(const float4*)(zn + 12);
        pw0 = *(const float4*)(wn);
        pw1 = *(const float4*)(wn + 64);
      }
      float zr[16] = {z0.x, z0.y, z0.z, z0.w, z1.x, z1.y, z1.z, z1.w,
                      z2.x, z2.y, z2.z, z2.w, z3.x, z3.y, z3.z, z3.w};
      float wr[8] = {w0.x, w0.y, w0.z, w0.w, w1.x, w1.y, w1.z, w1.w};
      #pragma unroll
      for (int i = 0; i < 16; ++i)
        #pragma unroll
        for (int j = 0; j < 8; ++j)
          acc[i][j] = fmaf(zr[i], wr[j], acc[i][j]);
    }

    // dist = |w|^2 - 2*dot. Per-thread k ascends over (g, j) -> strict <
    // keeps first-min; cross-thread ties resolved by index compare below.
    float wna[8] = {wn0.x, wn0.y, wn0.z, wn0.w, wn1.x, wn1.y, wn1.z, wn1.w};
    #pragma unroll
    for (int g = 0; g < 2; ++g)
      #pragma unroll
      for (int j = 0; j < 4; ++j) {
        int col = g * 4 + j;
        int kg = ktb + g * 64 + tx * 4 + j;
        float wn = wna[col];
        #pragma unroll
        for (int i = 0; i < 16; ++i) {
          float dist = fmaf(-2.f, acc[i][col], wn);
          if (dist < bestd[i]) { bestd[i] = dist; besti[i] = kg; }
        }
      }
  }

  // Reduce across the 16 tx threads sharing each n (same wave, width 16).
  #pragma unroll
  for (int i = 0; i < 16; ++i) {
    float bd = bestd[i]; int bi = besti[i];
    #pragma unroll
    for (int off = 8; off > 0; off >>= 1) {
      float od = __shfl_xor(bd, off, 16);
      int oi = __shfl_xor(bi, off, 16);
      if (od < bd || (od == bd && oi < bi)) { bd = od; bi = oi; }
    }
    if (tx == 0) {
      int n = n0 + ty * 16 + i;
      cd[blockIdx.y * N_TOK + n] = bd;
      ci[blockIdx.y * N_TOK + n] = bi;
    }
  }
}

// ---------------------------------------------------------------------------
// K2: reduce the GROUPS candidates per token; enc_sum atomics.
// Groups cover ascending k-ranges, so strict < keeps smallest index on tie.
__global__ void k_reduce(const float* __restrict__ cd, const int* __restrict__ ci,
                         int* __restrict__ idx, float* __restrict__ enc) {
  int n = blockIdx.x * 256 + threadIdx.x;
  float bd = cd[n]; int bi = ci[n];
  #pragma unroll
  for (int g = 1; g < GROUPS; ++g) {
    float od = cd[g * N_TOK + n];
    int oi = ci[g * N_TOK + n];
    if (od < bd) { bd = od; bi = oi; }
  }
  idx[n] = bi;
  atomicAdd(enc + bi, 1.0f);
}

// ---------------------------------------------------------------------------
// K3: z_q gather + straight-through output + loss partials + embed_sum atomics.
__global__ void k_quant(const float* __restrict__ z, const float* __restrict__ weight,
                        const int* __restrict__ idx, float* __restrict__ out,
                        float* __restrict__ embed_acc, float* __restrict__ ws) {
  int base = blockIdx.x * 1024 + threadIdx.x;
  float lsum = 0.f;
  #pragma unroll
  for (int i = 0; i < 4; ++i) {
    int e = base + i * 256;               // (b,c,hw) flat, same layout as z
    int c = (e >> 10) & 63;
    int n = ((e >> 16) << 10) | (e & 1023);
    int k = idx[n];
    float zv = z[e];
    float q = weight[k * EMB_D + c];
    out[e] = zv + (q - zv);               // straight-through value
    float d = q - zv;
    lsum += d * d;
    atomicAdd(embed_acc + k * EMB_D + c, zv);
  }
  #pragma unroll
  for (int off = 32; off > 0; off >>= 1) lsum += __shfl_xor(lsum, off, 64);
  __shared__ float red[4];
  int lane = threadIdx.x & 63, wv = threadIdx.x >> 6;
  if (lane == 0) red[wv] = lsum;
  __syncthreads();
  if (threadIdx.x == 0)
    atomicAdd(ws + WS_LOSS, red[0] + red[1] + red[2] + red[3]);
}

// ---------------------------------------------------------------------------
// K4: new_cluster_size (in place over enc_sum), n-sum, loss finalize.
__global__ void k_cluster(const float* __restrict__ cluster_in,
                          float* __restrict__ out, float* __restrict__ ws) {
  int k = blockIdx.x * 256 + threadIdx.x;
  float ncs = cluster_in[k] * 0.99f + 0.01f * out[OFF_CS + k];
  out[OFF_CS + k] = ncs;
  float s = ncs;
  #pragma unroll
  for (int off = 32; off > 0; off >>= 1) s += __shfl_xor(s, off, 64);
  __shared__ float red[4];
  int lane = threadIdx.x & 63, wv = threadIdx.x >> 6;
  if (lane == 0) red[wv] = s;
  __syncthreads();
  if (threadIdx.x == 0) atomicAdd(ws + WS_NSUM, red[0] + red[1] + red[2] + red[3]);
  if (blockIdx.x == 0 && threadIdx.x == 0)
    out[OFF_LOSS] = 0.25f * ws[WS_LOSS] * (1.0f / 1048576.0f);
}

// ---------------------------------------------------------------------------
// K5: smoothed cluster sizes -> new_weight; new_embed_avg (in place).
__global__ void k_final(const float* __restrict__ embed_avg,
                        float* __restrict__ out, const float* __restrict__ ws) {
  int e = blockIdx.x * 256 + threadIdx.x;   // < 524288
  int k = e >> 6;
  float ncs = out[OFF_CS + k];
  float nsum = ws[WS_NSUM];
  float sm = (ncs + 1e-5f) / (nsum + K_EMB * 1e-5f) * nsum;
  float ea = embed_avg[e] * 0.99f + 0.01f * out[OFF_EA + e];
  out[OFF_EA + e] = ea;
  out[OFF_W + e] = ea / sm;
}

// ---------------------------------------------------------------------------
extern "C" void kernel_launch(void* const* d_in, const int* in_sizes, int n_in,
                              void* d_out, int out_size, void* d_ws, size_t ws_size,
                              hipStream_t stream) {
  const float* z = (const float*)d_in[0];
  const float* weight = (const float*)d_in[1];
  const float* cluster = (const float*)d_in[2];
  const float* embed_avg = (const float*)d_in[3];
  float* out = (float*)d_out;
  float* ws = (float*)d_ws;
  float* wnorm = ws + WS_WNORM;
  int* idx = (int*)(ws + WS_IDX);
  float* wt = out + OUT_WT;               // scratch in z_q region
  float* cd = out + OUT_CD;
  int* ci = (int*)(out + OUT_CI);

  hipLaunchKernelGGL(k_prep, dim3(512), dim3(256), 0, stream, weight, out, ws);
  hipLaunchKernelGGL(k_argmin, dim3(N_TOK / TN, GROUPS), dim3(256), 0, stream,
                     z, wt, wnorm, cd, ci);
  hipLaunchKernelGGL(k_reduce, dim3(N_TOK / 256), dim3(256), 0, stream,
                     cd, ci, idx, out + OFF_CS);
  hipLaunchKernelGGL(k_quant, dim3(1024), dim3(256), 0, stream,
                     z, weight, idx, out, out + OFF_EA, ws);
  hipLaunchKernelGGL(k_cluster, dim3(K_EMB / 256), dim3(256), 0, stream,
                     cluster, out, ws);
  hipLaunchKernelGGL(k_final, dim3(524288 / 256), dim3(256), 0, stream,
                     embed_avg, out, ws);
}

// Round 10
// 460.129 us; speedup vs baseline: 1.4012x; 1.4012x over previous
//
#include <hip/hip_runtime.h>

// EMA Vector-Quantizer for MI355X (gfx950).
// N=16384 tokens, D=64, K=8192. Dominant cost: 16384x8192x64 fp32 GEMM for
// distance argmin (no fp32 MFMA on CDNA4 -> VALU, 109 us FMA-issue floor).
// Allocator mechanism (established R2-R9): VGPR budget = 512 / (LDS-implied
// waves/EU); kernel demand ~104. 256-thread blocks give either bad codegen
// (32KB LDS -> 5 blocks/CU target -> 64 VGPRs -> AGPR shuttles; R4 = 323us,
// fully issue-bound at 3x issue) or bad occupancy (61KB LDS -> 2 blocks/CU
// -> clean 104 VGPRs but 2 waves/SIMD -> 70% latency stall; R8 = 336us).
// R10 escape: 512-thread blocks + 64KB LDS -> 2 blocks/CU = 4 waves/SIMD
// (R4 proves this hides all latency) AND LDS-implied budget 128 >= demand
// -> clean codegen. Same per-thread structure as R8 (8n x 8k, acc[8][8]).

#define N_TOK 16384
#define K_EMB 8192
#define EMB_D 64
#define TN 256
#define GROUPS 8
#define KPG (K_EMB / GROUPS)   // 1024 codes per k-group, 8 kb-tiles of 128

// d_out flat layout (float32), in reference return order:
// z_q (1048576) | loss | new_weight (524288) | new_cluster_size (8192) | new_embed_avg (524288)
#define OFF_LOSS 1048576
#define OFF_W    1048577
#define OFF_CS   1572865
#define OFF_EA   1581057

// scratch inside the z_q region of out (all < 1048576, overwritten by k_quant)
#define OUT_WT 0                        // w_t[d][k]: 64 x 8192 = 524288 floats
#define OUT_CD 524288                   // cand dist [GROUPS][N_TOK] = 131072
#define OUT_CI (524288 + 131072)        // cand idx  [GROUPS][N_TOK] = 131072

// ws float offsets
#define WS_NSUM  0
#define WS_LOSS  1
#define WS_WNORM 16
#define WS_IDX   (WS_WNORM + K_EMB)

// ---------------------------------------------------------------------------
// K0: wnorm[k]; transpose weight -> w_t[d][k] (in out); zero accumulators.
__global__ void k_prep(const float* __restrict__ weight,
                       float* __restrict__ out, float* __restrict__ ws) {
  int gid = blockIdx.x * 256 + threadIdx.x;     // 0..131071
  int row = gid >> 4;                            // codebook row 0..8191
  int l16 = gid & 15;
  float4 w4 = *(const float4*)(weight + row * EMB_D + l16 * 4);
  float s = w4.x * w4.x + w4.y * w4.y + w4.z * w4.z + w4.w * w4.w;
  #pragma unroll
  for (int off = 8; off > 0; off >>= 1) s += __shfl_xor(s, off, 16);
  if (l16 == 0) ws[WS_WNORM + row] = s;

  // transposed copy: w_t[d*8192 + row], d = l16*4+c
  out[OUT_WT + (l16 * 4 + 0) * K_EMB + row] = w4.x;
  out[OUT_WT + (l16 * 4 + 1) * K_EMB + row] = w4.y;
  out[OUT_WT + (l16 * 4 + 2) * K_EMB + row] = w4.z;
  out[OUT_WT + (l16 * 4 + 3) * K_EMB + row] = w4.w;

  #pragma unroll
  for (int j = 0; j < 4; ++j) out[OFF_EA + gid * 4 + j] = 0.f;
  if (gid < K_EMB) out[OFF_CS + gid] = 0.f;
  if (gid == 0) { out[OFF_LOSS] = 0.f; ws[WS_NSUM] = 0.f; ws[WS_LOSS] = 0.f; }
}

// ---------------------------------------------------------------------------
// K1: distance argmin. Block = 512 threads (tx 16 x ty 32); block tile
// 256n x 128k per kb-iter; thread tile 8n x 8k (acc[8][8], demand ~104 VGPR).
// grid (64, 8) = 512 blocks = exactly 2/CU; z_s 64KB -> 2 blocks/CU ->
// 4 waves/SIMD resident AND 128-VGPR allocator budget (>= demand) -> clean
// codegen at latency-hiding occupancy.
// w fragment: k = ktb + g*64 + tx*4 + j -> contiguous dwordx4 from w_t rows.
// z fragment: LDS broadcast (4 distinct 16B addresses per wave-read).
__global__ __launch_bounds__(512) void k_argmin(
    const float* __restrict__ z, const float* __restrict__ wt,
    const float* __restrict__ wnorm, float* __restrict__ cd,
    int* __restrict__ ci) {
  __shared__ __align__(16) float z_s[EMB_D * TN];  // [d][n], 64 KB
  const int t = threadIdx.x;
  const int n0 = blockIdx.x * TN;
  const int kbase = blockIdx.y * KPG;
  // z is (b, c, hw): z_flat[n][d] = z[b*65536 + d*1024 + hw], n = b*1024+hw.
  // TN=256 stays within one 1024-aligned b-slab (n0 is a multiple of 256).
  const float* zb = z + ((n0 >> 10) << 16) + (n0 & 1023);

  #pragma unroll
  for (int i = 0; i < 8; ++i) {
    int f4 = i * 512 + t;                 // 0..4095 float4s
    int d = f4 >> 6, c4 = (f4 & 63) * 4;
    *(float4*)(z_s + d * TN + c4) = *(const float4*)(zb + d * 1024 + c4);
  }
  __syncthreads();                        // the only barrier

  const int tx = t & 15, ty = t >> 4;     // tx -> k (16), ty -> n slab (32)
  const float* zrow = z_s + ty * 8;       // this thread's 8-row n-slab
  float bestd[8];
  int besti[8];
  #pragma unroll
  for (int i = 0; i < 8; ++i) { bestd[i] = 3.4e38f; besti[i] = 0; }

  for (int kb = 0; kb < KPG / 128; ++kb) {
    const int ktb = kbase + kb * 128;
    float4 wn0 = *(const float4*)(wnorm + ktb + tx * 4);
    float4 wn1 = *(const float4*)(wnorm + ktb + 64 + tx * 4);

    float acc[8][8];
    #pragma unroll
    for (int i = 0; i < 8; ++i)
      #pragma unroll
      for (int j = 0; j < 8; ++j) acc[i][j] = 0.f;

    const float* wp = wt + ktb + tx * 4;  // row stride K_EMB per d
    #pragma unroll 4
    for (int d = 0; d < EMB_D; ++d) {
      float4 z0 = *(const float4*)(zrow + d * TN);
      float4 z1 = *(const float4*)(zrow + d * TN + 4);
      float4 w0 = *(const float4*)(wp);
      float4 w1 = *(const float4*)(wp + 64);
      wp += K_EMB;
      float zr[8] = {z0.x, z0.y, z0.z, z0.w, z1.x, z1.y, z1.z, z1.w};
      float wr[8] = {w0.x, w0.y, w0.z, w0.w, w1.x, w1.y, w1.z, w1.w};
      #pragma unroll
      for (int i = 0; i < 8; ++i)
        #pragma unroll
        for (int j = 0; j < 8; ++j)
          acc[i][j] = fmaf(zr[i], wr[j], acc[i][j]);
    }

    // dist = |w|^2 - 2*dot. Per-thread k ascends over (g, j) -> strict <
    // keeps first-min; cross-thread ties resolved by index compare below.
    float wna[8] = {wn0.x, wn0.y, wn0.z, wn0.w, wn1.x, wn1.y, wn1.z, wn1.w};
    #pragma unroll
    for (int g = 0; g < 2; ++g)
      #pragma unroll
      for (int j = 0; j < 4; ++j) {
        int col = g * 4 + j;
        int kg = ktb + g * 64 + tx * 4 + j;
        float wn = wna[col];
        #pragma unroll
        for (int i = 0; i < 8; ++i) {
          float dist = fmaf(-2.f, acc[i][col], wn);
          if (dist < bestd[i]) { bestd[i] = dist; besti[i] = kg; }
        }
      }
  }

  // Reduce across the 16 tx threads sharing each n (lanes of one wave,
  // width 16; tx == lane & 15 since ty is constant per 16-lane span).
  #pragma unroll
  for (int i = 0; i < 8; ++i) {
    float bd = bestd[i]; int bi = besti[i];
    #pragma unroll
    for (int off = 8; off > 0; off >>= 1) {
      float od = __shfl_xor(bd, off, 16);
      int oi = __shfl_xor(bi, off, 16);
      if (od < bd || (od == bd && oi < bi)) { bd = od; bi = oi; }
    }
    if (tx == 0) {
      int n = n0 + ty * 8 + i;
      cd[blockIdx.y * N_TOK + n] = bd;
      ci[blockIdx.y * N_TOK + n] = bi;
    }
  }
}

// ---------------------------------------------------------------------------
// K2: reduce the GROUPS candidates per token; enc_sum atomics.
// Groups cover ascending k-ranges, so strict < keeps smallest index on tie.
__global__ void k_reduce(const float* __restrict__ cd, const int* __restrict__ ci,
                         int* __restrict__ idx, float* __restrict__ enc) {
  int n = blockIdx.x * 256 + threadIdx.x;
  float bd = cd[n]; int bi = ci[n];
  #pragma unroll
  for (int g = 1; g < GROUPS; ++g) {
    float od = cd[g * N_TOK + n];
    int oi = ci[g * N_TOK + n];
    if (od < bd) { bd = od; bi = oi; }
  }
  idx[n] = bi;
  atomicAdd(enc + bi, 1.0f);
}

// ---------------------------------------------------------------------------
// K3: z_q gather + straight-through output + loss partials + embed_sum atomics.
__global__ void k_quant(const float* __restrict__ z, const float* __restrict__ weight,
                        const int* __restrict__ idx, float* __restrict__ out,
                        float* __restrict__ embed_acc, float* __restrict__ ws) {
  int base = blockIdx.x * 1024 + threadIdx.x;
  float lsum = 0.f;
  #pragma unroll
  for (int i = 0; i < 4; ++i) {
    int e = base + i * 256;               // (b,c,hw) flat, same layout as z
    int c = (e >> 10) & 63;
    int n = ((e >> 16) << 10) | (e & 1023);
    int k = idx[n];
    float zv = z[e];
    float q = weight[k * EMB_D + c];
    out[e] = zv + (q - zv);               // straight-through value
    float d = q - zv;
    lsum += d * d;
    atomicAdd(embed_acc + k * EMB_D + c, zv);
  }
  #pragma unroll
  for (int off = 32; off > 0; off >>= 1) lsum += __shfl_xor(lsum, off, 64);
  __shared__ float red[4];
  int lane = threadIdx.x & 63, wv = threadIdx.x >> 6;
  if (lane == 0) red[wv] = lsum;
  __syncthreads();
  if (threadIdx.x == 0)
    atomicAdd(ws + WS_LOSS, red[0] + red[1] + red[2] + red[3]);
}

// ---------------------------------------------------------------------------
// K4: new_cluster_size (in place over enc_sum), n-sum, loss finalize.
__global__ void k_cluster(const float* __restrict__ cluster_in,
                          float* __restrict__ out, float* __restrict__ ws) {
  int k = blockIdx.x * 256 + threadIdx.x;
  float ncs = cluster_in[k] * 0.99f + 0.01f * out[OFF_CS + k];
  out[OFF_CS + k] = ncs;
  float s = ncs;
  #pragma unroll
  for (int off = 32; off > 0; off >>= 1) s += __shfl_xor(s, off, 64);
  __shared__ float red[4];
  int lane = threadIdx.x & 63, wv = threadIdx.x >> 6;
  if (lane == 0) red[wv] = s;
  __syncthreads();
  if (threadIdx.x == 0) atomicAdd(ws + WS_NSUM, red[0] + red[1] + red[2] + red[3]);
  if (blockIdx.x == 0 && threadIdx.x == 0)
    out[OFF_LOSS] = 0.25f * ws[WS_LOSS] * (1.0f / 1048576.0f);
}

// ---------------------------------------------------------------------------
// K5: smoothed cluster sizes -> new_weight; new_embed_avg (in place).
__global__ void k_final(const float* __restrict__ embed_avg,
                        float* __restrict__ out, const float* __restrict__ ws) {
  int e = blockIdx.x * 256 + threadIdx.x;   // < 524288
  int k = e >> 6;
  float ncs = out[OFF_CS + k];
  float nsum = ws[WS_NSUM];
  float sm = (ncs + 1e-5f) / (nsum + K_EMB * 1e-5f) * nsum;
  float ea = embed_avg[e] * 0.99f + 0.01f * out[OFF_EA + e];
  out[OFF_EA + e] = ea;
  out[OFF_W + e] = ea / sm;
}

// ---------------------------------------------------------------------------
extern "C" void kernel_launch(void* const* d_in, const int* in_sizes, int n_in,
                              void* d_out, int out_size, void* d_ws, size_t ws_size,
                              hipStream_t stream) {
  const float* z = (const float*)d_in[0];
  const float* weight = (const float*)d_in[1];
  const float* cluster = (const float*)d_in[2];
  const float* embed_avg = (const float*)d_in[3];
  float* out = (float*)d_out;
  float* ws = (float*)d_ws;
  float* wnorm = ws + WS_WNORM;
  int* idx = (int*)(ws + WS_IDX);
  float* wt = out + OUT_WT;               // scratch in z_q region
  float* cd = out + OUT_CD;
  int* ci = (int*)(out + OUT_CI);

  hipLaunchKernelGGL(k_prep, dim3(512), dim3(256), 0, stream, weight, out, ws);
  hipLaunchKernelGGL(k_argmin, dim3(N_TOK / TN, GROUPS), dim3(512), 0, stream,
                     z, wt, wnorm, cd, ci);
  hipLaunchKernelGGL(k_reduce, dim3(N_TOK / 256), dim3(256), 0, stream,
                     cd, ci, idx, out + OFF_CS);
  hipLaunchKernelGGL(k_quant, dim3(1024), dim3(256), 0, stream,
                     z, weight, idx, out, out + OFF_EA, ws);
  hipLaunchKernelGGL(k_cluster, dim3(K_EMB / 256), dim3(256), 0, stream,
                     cluster, out, ws);
  hipLaunchKernelGGL(k_final, dim3(524288 / 256), dim3(256), 0, stream,
                     embed_avg, out, ws);
}

// Round 11
// 452.551 us; speedup vs baseline: 1.4247x; 1.0167x over previous
//
#include <hip/hip_runtime.h>

// EMA Vector-Quantizer for MI355X (gfx950).
// N=16384 tokens, D=64, K=8192. Dominant cost: 16384x8192x64 fp32 GEMM for
// distance argmin (no fp32 MFMA on CDNA4 -> VALU, 109 us FMA-issue floor).
// Mechanism map (R2-R10):
//  - arch-VGPR budget follows __launch_bounds__ 2nd arg (min waves/EU):
//    absent -> high-occupancy default -> 64 VGPRs -> acc[8][8] lives in
//    AGPRs -> v_accvgpr shuttles triple VALU issue (R4/R10: ~323us = 3x109).
//    (N,2) -> budget 256 (arch cap 128) -> clean 104-VGPR codegen (R8).
//  - Residency follows LDS: 64KB + 512-thread blocks -> 2 blocks/CU ->
//    4 waves/SIMD, which R4 showed fully hides z/w load latency.
// R11 = clean codegen AND latency-hiding occupancy: 512-thread blocks,
// 64KB z_s, __launch_bounds__(512, 2). Per-thread structure unchanged
// (8n x 8k, acc[8][8], demand ~104 VGPR).

#define N_TOK 16384
#define K_EMB 8192
#define EMB_D 64
#define TN 256
#define GROUPS 8
#define KPG (K_EMB / GROUPS)   // 1024 codes per k-group, 8 kb-tiles of 128

// d_out flat layout (float32), in reference return order:
// z_q (1048576) | loss | new_weight (524288) | new_cluster_size (8192) | new_embed_avg (524288)
#define OFF_LOSS 1048576
#define OFF_W    1048577
#define OFF_CS   1572865
#define OFF_EA   1581057

// scratch inside the z_q region of out (all < 1048576, overwritten by k_quant)
#define OUT_WT 0                        // w_t[d][k]: 64 x 8192 = 524288 floats
#define OUT_CD 524288                   // cand dist [GROUPS][N_TOK] = 131072
#define OUT_CI (524288 + 131072)        // cand idx  [GROUPS][N_TOK] = 131072

// ws float offsets
#define WS_NSUM  0
#define WS_LOSS  1
#define WS_WNORM 16
#define WS_IDX   (WS_WNORM + K_EMB)

// ---------------------------------------------------------------------------
// K0: wnorm[k]; transpose weight -> w_t[d][k] (in out); zero accumulators.
__global__ void k_prep(const float* __restrict__ weight,
                       float* __restrict__ out, float* __restrict__ ws) {
  int gid = blockIdx.x * 256 + threadIdx.x;     // 0..131071
  int row = gid >> 4;                            // codebook row 0..8191
  int l16 = gid & 15;
  float4 w4 = *(const float4*)(weight + row * EMB_D + l16 * 4);
  float s = w4.x * w4.x + w4.y * w4.y + w4.z * w4.z + w4.w * w4.w;
  #pragma unroll
  for (int off = 8; off > 0; off >>= 1) s += __shfl_xor(s, off, 16);
  if (l16 == 0) ws[WS_WNORM + row] = s;

  // transposed copy: w_t[d*8192 + row], d = l16*4+c
  out[OUT_WT + (l16 * 4 + 0) * K_EMB + row] = w4.x;
  out[OUT_WT + (l16 * 4 + 1) * K_EMB + row] = w4.y;
  out[OUT_WT + (l16 * 4 + 2) * K_EMB + row] = w4.z;
  out[OUT_WT + (l16 * 4 + 3) * K_EMB + row] = w4.w;

  #pragma unroll
  for (int j = 0; j < 4; ++j) out[OFF_EA + gid * 4 + j] = 0.f;
  if (gid < K_EMB) out[OFF_CS + gid] = 0.f;
  if (gid == 0) { out[OFF_LOSS] = 0.f; ws[WS_NSUM] = 0.f; ws[WS_LOSS] = 0.f; }
}

// ---------------------------------------------------------------------------
// K1: distance argmin. Block = 512 threads (tx 16 x ty 32); block tile
// 256n x 128k per kb-iter; thread tile 8n x 8k (acc[8][8], demand ~104 VGPR).
// grid (64, 8) = 512 blocks = exactly 2/CU; z_s 64KB -> 2 blocks/CU ->
// 4 waves/SIMD resident; __launch_bounds__(512,2) -> 256-VGPR budget ->
// clean codegen (no AGPR shuttles / spills).
// w fragment: k = ktb + g*64 + tx*4 + j -> contiguous dwordx4 from w_t rows
// (16 distinct addrs/wave -> 256B coalesced). z: LDS broadcast.
__global__ __launch_bounds__(512, 2) void k_argmin(
    const float* __restrict__ z, const float* __restrict__ wt,
    const float* __restrict__ wnorm, float* __restrict__ cd,
    int* __restrict__ ci) {
  __shared__ __align__(16) float z_s[EMB_D * TN];  // [d][n], 64 KB
  const int t = threadIdx.x;
  const int n0 = blockIdx.x * TN;
  const int kbase = blockIdx.y * KPG;
  // z is (b, c, hw): z_flat[n][d] = z[b*65536 + d*1024 + hw], n = b*1024+hw.
  // TN=256 stays within one 1024-aligned b-slab (n0 is a multiple of 256).
  const float* zb = z + ((n0 >> 10) << 16) + (n0 & 1023);

  #pragma unroll
  for (int i = 0; i < 8; ++i) {
    int f4 = i * 512 + t;                 // 0..4095 float4s
    int d = f4 >> 6, c4 = (f4 & 63) * 4;
    *(float4*)(z_s + d * TN + c4) = *(const float4*)(zb + d * 1024 + c4);
  }
  __syncthreads();                        // the only barrier

  const int tx = t & 15, ty = t >> 4;     // tx -> k (16), ty -> n slab (32)
  const float* zrow = z_s + ty * 8;       // this thread's 8-row n-slab
  float bestd[8];
  int besti[8];
  #pragma unroll
  for (int i = 0; i < 8; ++i) { bestd[i] = 3.4e38f; besti[i] = 0; }

  for (int kb = 0; kb < KPG / 128; ++kb) {
    const int ktb = kbase + kb * 128;
    float4 wn0 = *(const float4*)(wnorm + ktb + tx * 4);
    float4 wn1 = *(const float4*)(wnorm + ktb + 64 + tx * 4);

    float acc[8][8];
    #pragma unroll
    for (int i = 0; i < 8; ++i)
      #pragma unroll
      for (int j = 0; j < 8; ++j) acc[i][j] = 0.f;

    const float* wp = wt + ktb + tx * 4;  // row stride K_EMB per d
    #pragma unroll 4
    for (int d = 0; d < EMB_D; ++d) {
      float4 z0 = *(const float4*)(zrow + d * TN);
      float4 z1 = *(const float4*)(zrow + d * TN + 4);
      float4 w0 = *(const float4*)(wp);
      float4 w1 = *(const float4*)(wp + 64);
      wp += K_EMB;
      float zr[8] = {z0.x, z0.y, z0.z, z0.w, z1.x, z1.y, z1.z, z1.w};
      float wr[8] = {w0.x, w0.y, w0.z, w0.w, w1.x, w1.y, w1.z, w1.w};
      #pragma unroll
      for (int i = 0; i < 8; ++i)
        #pragma unroll
        for (int j = 0; j < 8; ++j)
          acc[i][j] = fmaf(zr[i], wr[j], acc[i][j]);
    }

    // dist = |w|^2 - 2*dot. Per-thread k ascends over (g, j) -> strict <
    // keeps first-min; cross-thread ties resolved by index compare below.
    float wna[8] = {wn0.x, wn0.y, wn0.z, wn0.w, wn1.x, wn1.y, wn1.z, wn1.w};
    #pragma unroll
    for (int g = 0; g < 2; ++g)
      #pragma unroll
      for (int j = 0; j < 4; ++j) {
        int col = g * 4 + j;
        int kg = ktb + g * 64 + tx * 4 + j;
        float wn = wna[col];
        #pragma unroll
        for (int i = 0; i < 8; ++i) {
          float dist = fmaf(-2.f, acc[i][col], wn);
          if (dist < bestd[i]) { bestd[i] = dist; besti[i] = kg; }
        }
      }
  }

  // Reduce across the 16 tx threads sharing each n (lanes of one wave,
  // width 16; tx == lane & 15 since ty is constant per 16-lane span).
  #pragma unroll
  for (int i = 0; i < 8; ++i) {
    float bd = bestd[i]; int bi = besti[i];
    #pragma unroll
    for (int off = 8; off > 0; off >>= 1) {
      float od = __shfl_xor(bd, off, 16);
      int oi = __shfl_xor(bi, off, 16);
      if (od < bd || (od == bd && oi < bi)) { bd = od; bi = oi; }
    }
    if (tx == 0) {
      int n = n0 + ty * 8 + i;
      cd[blockIdx.y * N_TOK + n] = bd;
      ci[blockIdx.y * N_TOK + n] = bi;
    }
  }
}

// ---------------------------------------------------------------------------
// K2: reduce the GROUPS candidates per token; enc_sum atomics.
// Groups cover ascending k-ranges, so strict < keeps smallest index on tie.
__global__ void k_reduce(const float* __restrict__ cd, const int* __restrict__ ci,
                         int* __restrict__ idx, float* __restrict__ enc) {
  int n = blockIdx.x * 256 + threadIdx.x;
  float bd = cd[n]; int bi = ci[n];
  #pragma unroll
  for (int g = 1; g < GROUPS; ++g) {
    float od = cd[g * N_TOK + n];
    int oi = ci[g * N_TOK + n];
    if (od < bd) { bd = od; bi = oi; }
  }
  idx[n] = bi;
  atomicAdd(enc + bi, 1.0f);
}

// ---------------------------------------------------------------------------
// K3: z_q gather + straight-through output + loss partials + embed_sum atomics.
__global__ void k_quant(const float* __restrict__ z, const float* __restrict__ weight,
                        const int* __restrict__ idx, float* __restrict__ out,
                        float* __restrict__ embed_acc, float* __restrict__ ws) {
  int base = blockIdx.x * 1024 + threadIdx.x;
  float lsum = 0.f;
  #pragma unroll
  for (int i = 0; i < 4; ++i) {
    int e = base + i * 256;               // (b,c,hw) flat, same layout as z
    int c = (e >> 10) & 63;
    int n = ((e >> 16) << 10) | (e & 1023);
    int k = idx[n];
    float zv = z[e];
    float q = weight[k * EMB_D + c];
    out[e] = zv + (q - zv);               // straight-through value
    float d = q - zv;
    lsum += d * d;
    atomicAdd(embed_acc + k * EMB_D + c, zv);
  }
  #pragma unroll
  for (int off = 32; off > 0; off >>= 1) lsum += __shfl_xor(lsum, off, 64);
  __shared__ float red[4];
  int lane = threadIdx.x & 63, wv = threadIdx.x >> 6;
  if (lane == 0) red[wv] = lsum;
  __syncthreads();
  if (threadIdx.x == 0)
    atomicAdd(ws + WS_LOSS, red[0] + red[1] + red[2] + red[3]);
}

// ---------------------------------------------------------------------------
// K4: new_cluster_size (in place over enc_sum), n-sum, loss finalize.
__global__ void k_cluster(const float* __restrict__ cluster_in,
                          float* __restrict__ out, float* __restrict__ ws) {
  int k = blockIdx.x * 256 + threadIdx.x;
  float ncs = cluster_in[k] * 0.99f + 0.01f * out[OFF_CS + k];
  out[OFF_CS + k] = ncs;
  float s = ncs;
  #pragma unroll
  for (int off = 32; off > 0; off >>= 1) s += __shfl_xor(s, off, 64);
  __shared__ float red[4];
  int lane = threadIdx.x & 63, wv = threadIdx.x >> 6;
  if (lane == 0) red[wv] = s;
  __syncthreads();
  if (threadIdx.x == 0) atomicAdd(ws + WS_NSUM, red[0] + red[1] + red[2] + red[3]);
  if (blockIdx.x == 0 && threadIdx.x == 0)
    out[OFF_LOSS] = 0.25f * ws[WS_LOSS] * (1.0f / 1048576.0f);
}

// ---------------------------------------------------------------------------
// K5: smoothed cluster sizes -> new_weight; new_embed_avg (in place).
__global__ void k_final(const float* __restrict__ embed_avg,
                        float* __restrict__ out, const float* __restrict__ ws) {
  int e = blockIdx.x * 256 + threadIdx.x;   // < 524288
  int k = e >> 6;
  float ncs = out[OFF_CS + k];
  float nsum = ws[WS_NSUM];
  float sm = (ncs + 1e-5f) / (nsum + K_EMB * 1e-5f) * nsum;
  float ea = embed_avg[e] * 0.99f + 0.01f * out[OFF_EA + e];
  out[OFF_EA + e] = ea;
  out[OFF_W + e] = ea / sm;
}

// ---------------------------------------------------------------------------
extern "C" void kernel_launch(void* const* d_in, const int* in_sizes, int n_in,
                              void* d_out, int out_size, void* d_ws, size_t ws_size,
                              hipStream_t stream) {
  const float* z = (const float*)d_in[0];
  const float* weight = (const float*)d_in[1];
  const float* cluster = (const float*)d_in[2];
  const float* embed_avg = (const float*)d_in[3];
  float* out = (float*)d_out;
  float* ws = (float*)d_ws;
  float* wnorm = ws + WS_WNORM;
  int* idx = (int*)(ws + WS_IDX);
  float* wt = out + OUT_WT;               // scratch in z_q region
  float* cd = out + OUT_CD;
  int* ci = (int*)(out + OUT_CI);

  hipLaunchKernelGGL(k_prep, dim3(512), dim3(256), 0, stream, weight, out, ws);
  hipLaunchKernelGGL(k_argmin, dim3(N_TOK / TN, GROUPS), dim3(512), 0, stream,
                     z, wt, wnorm, cd, ci);
  hipLaunchKernelGGL(k_reduce, dim3(N_TOK / 256), dim3(256), 0, stream,
                     cd, ci, idx, out + OFF_CS);
  hipLaunchKernelGGL(k_quant, dim3(1024), dim3(256), 0, stream,
                     z, weight, idx, out, out + OFF_EA, ws);
  hipLaunchKernelGGL(k_cluster, dim3(K_EMB / 256), dim3(256), 0, stream,
                     cluster, out, ws);
  hipLaunchKernelGGL(k_final, dim3(524288 / 256), dim3(256), 0, stream,
                     embed_avg, out, ws);
}

// Round 12
// 414.666 us; speedup vs baseline: 1.5548x; 1.0914x over previous
//
#include <hip/hip_runtime.h>

// EMA Vector-Quantizer for MI355X (gfx950).
// N=16384 tokens, D=64, K=8192. Dominant cost: 16384x8192x64 fp32 GEMM for
// distance argmin (no fp32 MFMA on CDNA4).
// R2-R11 finding: three structurally different k_argmin variants (w-in-LDS,
// w-global at 2 or 4 waves/SIMD, clean or AGPR codegen) ALL land 320-340us.
// The invariant tracks plain v_fma_f32 VALU rate (m07 ubench ceiling: 103 TF
// = 65% of spec), not any memory pipe. R12 attacks the rate itself: CDNA3+
// v_pk_fma_f32 (VOP3P packed fp32, 2 FMA/lane/inst). Inner loop rewritten as
// <2 x float> elementwise-fma over n-row pairs -> LLVM lowers to v_pk_fma_f32.
// Per-(n,k) fused-FMA chain (d ascending) is bit-identical to the scalar
// version -> outputs unchanged. Shell identical to R11 (512-thr blocks,
// 64KB z_s LDS, grid (64,8) = 2 blocks/CU).

#define N_TOK 16384
#define K_EMB 8192
#define EMB_D 64
#define TN 256
#define GROUPS 8
#define KPG (K_EMB / GROUPS)   // 1024 codes per k-group, 8 kb-tiles of 128

typedef float v2f __attribute__((ext_vector_type(2)));

// d_out flat layout (float32), in reference return order:
// z_q (1048576) | loss | new_weight (524288) | new_cluster_size (8192) | new_embed_avg (524288)
#define OFF_LOSS 1048576
#define OFF_W    1048577
#define OFF_CS   1572865
#define OFF_EA   1581057

// scratch inside the z_q region of out (all < 1048576, overwritten by k_quant)
#define OUT_WT 0                        // w_t[d][k]: 64 x 8192 = 524288 floats
#define OUT_CD 524288                   // cand dist [GROUPS][N_TOK] = 131072
#define OUT_CI (524288 + 131072)        // cand idx  [GROUPS][N_TOK] = 131072

// ws float offsets
#define WS_NSUM  0
#define WS_LOSS  1
#define WS_WNORM 16
#define WS_IDX   (WS_WNORM + K_EMB)

// ---------------------------------------------------------------------------
// K0: wnorm[k]; transpose weight -> w_t[d][k] (in out); zero accumulators.
__global__ void k_prep(const float* __restrict__ weight,
                       float* __restrict__ out, float* __restrict__ ws) {
  int gid = blockIdx.x * 256 + threadIdx.x;     // 0..131071
  int row = gid >> 4;                            // codebook row 0..8191
  int l16 = gid & 15;
  float4 w4 = *(const float4*)(weight + row * EMB_D + l16 * 4);
  float s = w4.x * w4.x + w4.y * w4.y + w4.z * w4.z + w4.w * w4.w;
  #pragma unroll
  for (int off = 8; off > 0; off >>= 1) s += __shfl_xor(s, off, 16);
  if (l16 == 0) ws[WS_WNORM + row] = s;

  // transposed copy: w_t[d*8192 + row], d = l16*4+c
  out[OUT_WT + (l16 * 4 + 0) * K_EMB + row] = w4.x;
  out[OUT_WT + (l16 * 4 + 1) * K_EMB + row] = w4.y;
  out[OUT_WT + (l16 * 4 + 2) * K_EMB + row] = w4.z;
  out[OUT_WT + (l16 * 4 + 3) * K_EMB + row] = w4.w;

  #pragma unroll
  for (int j = 0; j < 4; ++j) out[OFF_EA + gid * 4 + j] = 0.f;
  if (gid < K_EMB) out[OFF_CS + gid] = 0.f;
  if (gid == 0) { out[OFF_LOSS] = 0.f; ws[WS_NSUM] = 0.f; ws[WS_LOSS] = 0.f; }
}

// ---------------------------------------------------------------------------
// K1: distance argmin. Block = 512 threads (tx 16 x ty 32); block tile
// 256n x 128k per kb-iter; thread tile 8n x 8k, acc as 4x8 v2f (n-row pairs).
// grid (64, 8) = 512 blocks = exactly 2/CU; z_s 64KB -> 4 waves/SIMD.
// Inner loop: v_pk_fma_f32 via <2 x float> __builtin_elementwise_fma.
// w fragment: k = ktb + g*64 + tx*4 + j -> contiguous dwordx4 from w_t rows
// (16 distinct addrs/wave -> 256B coalesced, L1-resident). z: LDS broadcast.
__global__ __launch_bounds__(512, 2) void k_argmin(
    const float* __restrict__ z, const float* __restrict__ wt,
    const float* __restrict__ wnorm, float* __restrict__ cd,
    int* __restrict__ ci) {
  __shared__ __align__(16) float z_s[EMB_D * TN];  // [d][n], 64 KB
  const int t = threadIdx.x;
  const int n0 = blockIdx.x * TN;
  const int kbase = blockIdx.y * KPG;
  // z is (b, c, hw): z_flat[n][d] = z[b*65536 + d*1024 + hw], n = b*1024+hw.
  // TN=256 stays within one 1024-aligned b-slab (n0 is a multiple of 256).
  const float* zb = z + ((n0 >> 10) << 16) + (n0 & 1023);

  #pragma unroll
  for (int i = 0; i < 8; ++i) {
    int f4 = i * 512 + t;                 // 0..4095 float4s
    int d = f4 >> 6, c4 = (f4 & 63) * 4;
    *(float4*)(z_s + d * TN + c4) = *(const float4*)(zb + d * 1024 + c4);
  }
  __syncthreads();                        // the only barrier

  const int tx = t & 15, ty = t >> 4;     // tx -> k (16), ty -> n slab (32)
  const float* zrow = z_s + ty * 8;       // this thread's 8-row n-slab
  float bestd[8];
  int besti[8];
  #pragma unroll
  for (int i = 0; i < 8; ++i) { bestd[i] = 3.4e38f; besti[i] = 0; }

  for (int kb = 0; kb < KPG / 128; ++kb) {
    const int ktb = kbase + kb * 128;
    float4 wn0 = *(const float4*)(wnorm + ktb + tx * 4);
    float4 wn1 = *(const float4*)(wnorm + ktb + 64 + tx * 4);

    v2f acc2[4][8];                       // [n-pair][k]; .x=row 2p, .y=row 2p+1
    #pragma unroll
    for (int p = 0; p < 4; ++p)
      #pragma unroll
      for (int j = 0; j < 8; ++j) acc2[p][j] = (v2f)(0.f);

    const float* wp = wt + ktb + tx * 4;  // row stride K_EMB per d
    #pragma unroll 4
    for (int d = 0; d < EMB_D; ++d) {
      const v2f* z2p = (const v2f*)(zrow + d * TN);  // 4 n-row pairs
      v2f z2[4] = {z2p[0], z2p[1], z2p[2], z2p[3]};
      float4 w0 = *(const float4*)(wp);
      float4 w1 = *(const float4*)(wp + 64);
      wp += K_EMB;
      float wr[8] = {w0.x, w0.y, w0.z, w0.w, w1.x, w1.y, w1.z, w1.w};
      #pragma unroll
      for (int j = 0; j < 8; ++j) {
        v2f w2 = {wr[j], wr[j]};
        #pragma unroll
        for (int p = 0; p < 4; ++p)
          acc2[p][j] = __builtin_elementwise_fma(z2[p], w2, acc2[p][j]);
      }
    }

    // dist = |w|^2 - 2*dot. Per-thread k ascends over (g, j) -> strict <
    // keeps first-min; cross-thread ties resolved by index compare below.
    float wna[8] = {wn0.x, wn0.y, wn0.z, wn0.w, wn1.x, wn1.y, wn1.z, wn1.w};
    #pragma unroll
    for (int g = 0; g < 2; ++g)
      #pragma unroll
      for (int j = 0; j < 4; ++j) {
        int col = g * 4 + j;
        int kg = ktb + g * 64 + tx * 4 + j;
        float wn = wna[col];
        #pragma unroll
        for (int i = 0; i < 8; ++i) {
          float dot = (i & 1) ? acc2[i >> 1][col].y : acc2[i >> 1][col].x;
          float dist = fmaf(-2.f, dot, wn);
          if (dist < bestd[i]) { bestd[i] = dist; besti[i] = kg; }
        }
      }
  }

  // Reduce across the 16 tx threads sharing each n (lanes of one wave,
  // width 16; tx == lane & 15 since ty is constant per 16-lane span).
  #pragma unroll
  for (int i = 0; i < 8; ++i) {
    float bd = bestd[i]; int bi = besti[i];
    #pragma unroll
    for (int off = 8; off > 0; off >>= 1) {
      float od = __shfl_xor(bd, off, 16);
      int oi = __shfl_xor(bi, off, 16);
      if (od < bd || (od == bd && oi < bi)) { bd = od; bi = oi; }
    }
    if (tx == 0) {
      int n = n0 + ty * 8 + i;
      cd[blockIdx.y * N_TOK + n] = bd;
      ci[blockIdx.y * N_TOK + n] = bi;
    }
  }
}

// ---------------------------------------------------------------------------
// K2: reduce the GROUPS candidates per token; enc_sum atomics.
// Groups cover ascending k-ranges, so strict < keeps smallest index on tie.
__global__ void k_reduce(const float* __restrict__ cd, const int* __restrict__ ci,
                         int* __restrict__ idx, float* __restrict__ enc) {
  int n = blockIdx.x * 256 + threadIdx.x;
  float bd = cd[n]; int bi = ci[n];
  #pragma unroll
  for (int g = 1; g < GROUPS; ++g) {
    float od = cd[g * N_TOK + n];
    int oi = ci[g * N_TOK + n];
    if (od < bd) { bd = od; bi = oi; }
  }
  idx[n] = bi;
  atomicAdd(enc + bi, 1.0f);
}

// ---------------------------------------------------------------------------
// K3: z_q gather + straight-through output + loss partials + embed_sum atomics.
__global__ void k_quant(const float* __restrict__ z, const float* __restrict__ weight,
                        const int* __restrict__ idx, float* __restrict__ out,
                        float* __restrict__ embed_acc, float* __restrict__ ws) {
  int base = blockIdx.x * 1024 + threadIdx.x;
  float lsum = 0.f;
  #pragma unroll
  for (int i = 0; i < 4; ++i) {
    int e = base + i * 256;               // (b,c,hw) flat, same layout as z
    int c = (e >> 10) & 63;
    int n = ((e >> 16) << 10) | (e & 1023);
    int k = idx[n];
    float zv = z[e];
    float q = weight[k * EMB_D + c];
    out[e] = zv + (q - zv);               // straight-through value
    float d = q - zv;
    lsum += d * d;
    atomicAdd(embed_acc + k * EMB_D + c, zv);
  }
  #pragma unroll
  for (int off = 32; off > 0; off >>= 1) lsum += __shfl_xor(lsum, off, 64);
  __shared__ float red[4];
  int lane = threadIdx.x & 63, wv = threadIdx.x >> 6;
  if (lane == 0) red[wv] = lsum;
  __syncthreads();
  if (threadIdx.x == 0)
    atomicAdd(ws + WS_LOSS, red[0] + red[1] + red[2] + red[3]);
}

// ---------------------------------------------------------------------------
// K4: new_cluster_size (in place over enc_sum), n-sum, loss finalize.
__global__ void k_cluster(const float* __restrict__ cluster_in,
                          float* __restrict__ out, float* __restrict__ ws) {
  int k = blockIdx.x * 256 + threadIdx.x;
  float ncs = cluster_in[k] * 0.99f + 0.01f * out[OFF_CS + k];
  out[OFF_CS + k] = ncs;
  float s = ncs;
  #pragma unroll
  for (int off = 32; off > 0; off >>= 1) s += __shfl_xor(s, off, 64);
  __shared__ float red[4];
  int lane = threadIdx.x & 63, wv = threadIdx.x >> 6;
  if (lane == 0) red[wv] = s;
  __syncthreads();
  if (threadIdx.x == 0) atomicAdd(ws + WS_NSUM, red[0] + red[1] + red[2] + red[3]);
  if (blockIdx.x == 0 && threadIdx.x == 0)
    out[OFF_LOSS] = 0.25f * ws[WS_LOSS] * (1.0f / 1048576.0f);
}

// ---------------------------------------------------------------------------
// K5: smoothed cluster sizes -> new_weight; new_embed_avg (in place).
__global__ void k_final(const float* __restrict__ embed_avg,
                        float* __restrict__ out, const float* __restrict__ ws) {
  int e = blockIdx.x * 256 + threadIdx.x;   // < 524288
  int k = e >> 6;
  float ncs = out[OFF_CS + k];
  float nsum = ws[WS_NSUM];
  float sm = (ncs + 1e-5f) / (nsum + K_EMB * 1e-5f) * nsum;
  float ea = embed_avg[e] * 0.99f + 0.01f * out[OFF_EA + e];
  out[OFF_EA + e] = ea;
  out[OFF_W + e] = ea / sm;
}

// ---------------------------------------------------------------------------
extern "C" void kernel_launch(void* const* d_in, const int* in_sizes, int n_in,
                              void* d_out, int out_size, void* d_ws, size_t ws_size,
                              hipStream_t stream) {
  const float* z = (const float*)d_in[0];
  const float* weight = (const float*)d_in[1];
  const float* cluster = (const float*)d_in[2];
  const float* embed_avg = (const float*)d_in[3];
  float* out = (float*)d_out;
  float* ws = (float*)d_ws;
  float* wnorm = ws + WS_WNORM;
  int* idx = (int*)(ws + WS_IDX);
  float* wt = out + OUT_WT;               // scratch in z_q region
  float* cd = out + OUT_CD;
  int* ci = (int*)(out + OUT_CI);

  hipLaunchKernelGGL(k_prep, dim3(512), dim3(256), 0, stream, weight, out, ws);
  hipLaunchKernelGGL(k_argmin, dim3(N_TOK / TN, GROUPS), dim3(512), 0, stream,
                     z, wt, wnorm, cd, ci);
  hipLaunchKernelGGL(k_reduce, dim3(N_TOK / 256), dim3(256), 0, stream,
                     cd, ci, idx, out + OFF_CS);
  hipLaunchKernelGGL(k_quant, dim3(1024), dim3(256), 0, stream,
                     z, weight, idx, out, out + OFF_EA, ws);
  hipLaunchKernelGGL(k_cluster, dim3(K_EMB / 256), dim3(256), 0, stream,
                     cluster, out, ws);
  hipLaunchKernelGGL(k_final, dim3(524288 / 256), dim3(256), 0, stream,
                     embed_avg, out, ws);
}